// Round 1
// 368.940 us; speedup vs baseline: 1.0206x; 1.0206x over previous
//
#include <hip/hip_runtime.h>
#include <math.h>

// Problem constants (from reference): B=256, N=1024, H=256, K=5
#define BGRAPHS 256
#define NNODES  1024
#define HDIM    256
#define KSEL    5
#define NEG_SLOPE 0.01f

#define NPB    128   // nodes per block-chunk (1024/128 = 8 chunks per graph)
#define UNROLL 4     // iterations (4 nodes each) in flight per wave

// Monotone float->uint map: a > b  <=>  ordf(a) > ordf(b)
__device__ __forceinline__ unsigned int ordf(float f) {
    unsigned int u = __float_as_uint(f);
    return (u & 0x80000000u) ? ~u : (u | 0x80000000u);
}

// ---------------------------------------------------------------------------
// Kernel 1: per-node max over H=256 f32 channels -> keys[node]; -inf for
// padded nodes. 2048 blocks x 256 threads; each block owns one 128-node chunk
// of ONE graph, clamped to the graph's valid prefix (reads ~134 MB of the
// 268 MB h). NEW: chunk id is swizzled (x997 mod 2048, bijective) so that any
// arithmetic-progression block->CU placement receives chunks from ~8
// DIFFERENT graphs -> per-CU work ~ sum of 8 independent chunk loads instead
// of one graph's full n_nodes (tail ~2x mean under a linear mapping).
// ---------------------------------------------------------------------------
__global__ __launch_bounds__(256) void node_max_kernel(
        const float* __restrict__ h,
        const int* __restrict__ n_nodes,
        float* __restrict__ keys) {
    __shared__ float keys_s[NPB];
    const int t    = threadIdx.x;
    const int wave = t >> 6;
    const int lane = t & 63;

    const int cid = (int)((blockIdx.x * 997u) & 2047u);   // swizzled chunk id
    const long long base = (long long)cid * NPB;          // first node of chunk
    const int b   = (int)(base >> 10);                    // graph id (block-uniform)
    const int nb0 = (int)(base & 1023);                   // node-in-graph of keys_s[0]
    int nv = n_nodes[b] - nb0;                            // valid nodes in this chunk
    nv = nv < 0 ? 0 : (nv > NPB ? NPB : nv);

    if (t < NPB) keys_s[t] = -INFINITY;                   // tail default
    __syncthreads();

    const float4* __restrict__ h4 = (const float4*)h;
    // float4 index for (node, lane): node*64 + lane
    const long long idx = (base + wave) * 64 + lane;

    // Each iteration ii covers nodes [ii*4, ii*4+4) (one per wave).
    const int niter = (nv + 3) >> 2;                      // only valid prefix
    for (int ii = 0; ii < niter; ii += UNROLL) {
        float4 d[UNROLL];
        bool   act[UNROLL];
#pragma unroll
        for (int u = 0; u < UNROLL; ++u) {
            int local = (ii + u) * 4 + wave;              // wave-uniform
            act[u] = (local < nv) && (ii + u < niter);
            if (act[u])
                d[u] = h4[idx + (long long)(ii + u) * 4 * 64];
        }
#pragma unroll
        for (int u = 0; u < UNROLL; ++u) {
            if (act[u]) {                                 // wave-uniform branch
                float m = fmaxf(fmaxf(d[u].x, d[u].y), fmaxf(d[u].z, d[u].w));
#pragma unroll
                for (int off = 32; off > 0; off >>= 1)
                    m = fmaxf(m, __shfl_xor(m, off, 64));
                if (lane == 0)
                    keys_s[(ii + u) * 4 + wave] = m;
            }
        }
    }
    __syncthreads();
    if (t < NPB)
        keys[base + t] = keys_s[t];                       // coalesced 512 B store
}

// ---------------------------------------------------------------------------
// Kernel 2: one block (256 threads, 4 waves) per graph. Rewritten from the
// ~100-barrier tree-reduce version to EXACTLY 8 barriers:
//   - keys held in registers (float4/thread); top-5 via packed uint64
//     (ordf(val)<<32 | (1023-idx)) so a single 64-bit max implements the
//     (val desc, idx asc) top_k tie-break; wave shfl butterfly + per-round
//     LDS slot -> 1 barrier/round (5 total).
//   - all 5 rows gathered concurrently (1 barrier), rank-sorted in ONE fused
//     float4 LDS scan (1 barrier after scatter).
//   - logits via wave shuffle reduce + one cross-wave LDS combine (1 barrier);
//     softmax computed redundantly per-thread in registers (no serial
//     thread-0 section, no extra barrier).
// Invalid rows (key == -inf) are zeroed but still participate in the softmax
// (matches reference: their logit is leaky_relu(c_b)).
// ---------------------------------------------------------------------------
__global__ __launch_bounds__(256) void topk_attn_kernel(
        const float* __restrict__ h,
        const float* __restrict__ q,
        const float* __restrict__ W,    // [2H] flat: W1 = W[0:H], W2 = W[H:2H]
        const float* __restrict__ keys,
        float* __restrict__ out) {
    __shared__ float cb_red[4];
    __shared__ unsigned long long wmax[KSEL][4];   // per-round slots: 1 barrier/round
    __shared__ __align__(16) float row_s[KSEL][HDIM];
    __shared__ __align__(16) float sorted_s[KSEL][HDIM];
    __shared__ float dred[4][KSEL];

    const int t    = threadIdx.x;
    const int lane = t & 63;
    const int wave = t >> 6;
    const int b    = blockIdx.x;

    // ---- register loads: 4 keys/thread, q, W1, W2 ----
    const float4 kv = ((const float4*)(keys + b * NNODES))[t];
    const float qv = q[b * HDIM + t];
    const float w1 = W[t];
    const float w2 = W[HDIM + t];

    // packed keys: high 32 = ordered float, low 32 = 1023-idx (asc-idx tiebreak)
    unsigned long long pk0 = ((unsigned long long)ordf(kv.x) << 32) | (unsigned int)(1023 - (4 * t + 0));
    unsigned long long pk1 = ((unsigned long long)ordf(kv.y) << 32) | (unsigned int)(1023 - (4 * t + 1));
    unsigned long long pk2 = ((unsigned long long)ordf(kv.z) << 32) | (unsigned int)(1023 - (4 * t + 2));
    unsigned long long pk3 = ((unsigned long long)ordf(kv.w) << 32) | (unsigned int)(1023 - (4 * t + 3));

    // ---- c_b partial: wave butterfly now, cross-wave combine read later ----
    float c = qv * w2;
#pragma unroll
    for (int off = 32; off > 0; off >>= 1)
        c += __shfl_xor(c, off, 64);
    if (lane == 0) cb_red[wave] = c;     // covered by round-0 barrier below

    // ---- top-5: 5 rounds, 1 barrier each ----
    const unsigned int ORD_NINF = 0x007FFFFFu;   // ordf(-inf)
    int widx[KSEL];
    int wvalid[KSEL];
#pragma unroll
    for (int k = 0; k < KSEL; ++k) {
        unsigned long long p = pk0;
        p = pk1 > p ? pk1 : p;
        p = pk2 > p ? pk2 : p;
        p = pk3 > p ? pk3 : p;
#pragma unroll
        for (int off = 32; off > 0; off >>= 1) {
            unsigned long long o = __shfl_xor(p, off, 64);
            p = o > p ? o : p;
        }
        if (lane == 0) wmax[k][wave] = p;
        __syncthreads();
        unsigned long long p0 = wmax[k][0], p1 = wmax[k][1];
        unsigned long long p2 = wmax[k][2], p3 = wmax[k][3];
        p = p0 > p1 ? p0 : p1;
        unsigned long long pq = p2 > p3 ? p2 : p3;
        p = pq > p ? pq : p;

        const int idx = 1023 - (int)(unsigned int)(p & 0xFFFFFFFFull);
        widx[k]   = idx;
        wvalid[k] = ((unsigned int)(p >> 32)) != ORD_NINF;

        // exclude winner (static indexing only — no scratch)
        const bool own = (idx >> 2) == t;
        const int  s   = idx & 3;
        pk0 = (own && s == 0) ? 0ull : pk0;
        pk1 = (own && s == 1) ? 0ull : pk1;
        pk2 = (own && s == 2) ? 0ull : pk2;
        pk3 = (own && s == 3) ? 0ull : pk3;
    }

    // ---- gather all 5 rows concurrently (loads pipelined, 1 barrier) ----
    float vk[KSEL];
#pragma unroll
    for (int k = 0; k < KSEL; ++k) {
        float v = 0.0f;
        if (wvalid[k])                                   // block-uniform branch
            v = h[((long long)b * NNODES + widx[k]) * HDIM + t];
        vk[k] = v;
    }
#pragma unroll
    for (int k = 0; k < KSEL; ++k)
        row_s[k][t] = vk[k];
    __syncthreads();

    // ---- fused rank-sort of all 5 rows (ascending, (val, idx) total order) ----
    int rk[KSEL] = {0, 0, 0, 0, 0};
    const float4* r4 = (const float4*)&row_s[0][0];      // [KSEL][HDIM/4]
#pragma unroll 4
    for (int jj = 0; jj < HDIM / 4; ++jj) {
        const int j = jj * 4;
#pragma unroll
        for (int k = 0; k < KSEL; ++k) {
            float4 a = r4[k * (HDIM / 4) + jj];          // uniform addr: LDS broadcast
            rk[k] += (int)((a.x < vk[k]) | ((a.x == vk[k]) & (j     < t)));
            rk[k] += (int)((a.y < vk[k]) | ((a.y == vk[k]) & (j + 1 < t)));
            rk[k] += (int)((a.z < vk[k]) | ((a.z == vk[k]) & (j + 2 < t)));
            rk[k] += (int)((a.w < vk[k]) | ((a.w == vk[k]) & (j + 3 < t)));
        }
    }
#pragma unroll
    for (int k = 0; k < KSEL; ++k)
        sorted_s[k][rk[k]] = vk[k];                      // bijection: total order
    __syncthreads();

    // ---- logits: 5 dots via wave shfl + one cross-wave combine ----
    float sv[KSEL], d[KSEL];
#pragma unroll
    for (int k = 0; k < KSEL; ++k) {
        sv[k] = sorted_s[k][t];
        d[k]  = sv[k] * w1;
    }
#pragma unroll
    for (int off = 32; off > 0; off >>= 1) {
#pragma unroll
        for (int k = 0; k < KSEL; ++k)
            d[k] += __shfl_xor(d[k], off, 64);
    }
    if (lane == 0) {
#pragma unroll
        for (int k = 0; k < KSEL; ++k)
            dred[wave][k] = d[k];
    }
    __syncthreads();

    // ---- leaky-relu + softmax, redundantly per-thread in registers ----
    const float cb = cb_red[0] + cb_red[1] + cb_red[2] + cb_red[3];
    float lg[KSEL];
    float mx = -INFINITY;
#pragma unroll
    for (int k = 0; k < KSEL; ++k) {
        float x = dred[0][k] + dred[1][k] + dred[2][k] + dred[3][k] + cb;
        lg[k] = (x > 0.0f) ? x : NEG_SLOPE * x;
        mx = fmaxf(mx, lg[k]);
    }
    float den = 0.0f;
#pragma unroll
    for (int k = 0; k < KSEL; ++k) { lg[k] = expf(lg[k] - mx); den += lg[k]; }
    const float inv_den = 1.0f / den;

    // ---- weighted sum, f32 store ----
    float o = 0.0f;
#pragma unroll
    for (int k = 0; k < KSEL; ++k)
        o += (lg[k] * inv_den) * sv[k];

    out[b * HDIM + t] = o;
}

extern "C" void kernel_launch(void* const* d_in, const int* in_sizes, int n_in,
                              void* d_out, int out_size, void* d_ws, size_t ws_size,
                              hipStream_t stream) {
    // Inputs (setup_inputs order, reference dtypes): h [B,N,H] f32,
    // n_nodes [B] int32, attention_query [B,H] f32, W [1,2H] f32.
    // Output: [B,H] f32.
    const float* h  = (const float*)d_in[0];
    const int*   nn = (const int*)d_in[1];
    const float* q  = (const float*)d_in[2];
    const float* W  = (const float*)d_in[3];
    float*       out = (float*)d_out;

    float* keys = (float*)d_ws;   // B*N floats = 1 MiB, fully overwritten every call

    // Pass 1: per-node max, reading ONLY the valid node prefix per graph
    // (~134 MB of 268 MB). 2048 blocks, swizzled 128-node chunks for balance.
    node_max_kernel<<<(BGRAPHS * NNODES) / NPB, 256, 0, stream>>>(h, nn, keys);
    // Pass 2: per-graph top-5 + sort + attention (8 barriers total)
    topk_attn_kernel<<<BGRAPHS, 256, 0, stream>>>(h, q, W, keys, out);
}

// Round 2
// 368.885 us; speedup vs baseline: 1.0207x; 1.0001x over previous
//
#include <hip/hip_runtime.h>
#include <math.h>

// Problem constants (from reference): B=256, N=1024, H=256, K=5
#define BGRAPHS 256
#define NNODES  1024
#define HDIM    256
#define KSEL    5
#define NEG_SLOPE 0.01f

#define NPB    64    // nodes per block-chunk (1024/64 = 16 chunks per graph)
#define UNROLL 4     // iterations (4 nodes each) in flight per wave

// Monotone float->uint map: a > b  <=>  ordf(a) > ordf(b)
__device__ __forceinline__ unsigned int ordf(float f) {
    unsigned int u = __float_as_uint(f);
    return (u & 0x80000000u) ? ~u : (u | 0x80000000u);
}

// ---------------------------------------------------------------------------
// Kernel 1: per-node max over H=256 f32 channels -> keys[node]; -inf for
// padded nodes. 4096 blocks x 256 threads; each block owns one 64-node chunk
// of ONE graph, clamped to the graph's valid prefix (reads ~134 MB of the
// 268 MB h).
// NPB=64 (not 128): at NPB=128 the grid was 2048 blocks = exactly the
// 8-blocks/CU residency limit, so ALL blocks were co-resident and the HW
// dispatcher never rebalanced -> total time = max over CUs of a static
// 8-chunk sum (~2x mean for the worst CU, since chunk work ~ U[0,128]).
// At 4096 blocks half the grid queues behind the resident set and flows to
// whichever CU frees first -> tail shrinks to ~one 64-node chunk.
// Chunk id swizzled (x997 mod 4096, bijective) so the initial resident set
// also draws chunks from many different graphs.
// ---------------------------------------------------------------------------
__global__ __launch_bounds__(256) void node_max_kernel(
        const float* __restrict__ h,
        const int* __restrict__ n_nodes,
        float* __restrict__ keys) {
    __shared__ float keys_s[NPB];
    const int t    = threadIdx.x;
    const int wave = t >> 6;
    const int lane = t & 63;

    const int cid = (int)((blockIdx.x * 997u) & 4095u);   // swizzled chunk id
    const long long base = (long long)cid * NPB;          // first node of chunk
    const int b   = (int)(base >> 10);                    // graph id (block-uniform)
    const int nb0 = (int)(base & 1023);                   // node-in-graph of keys_s[0]
    int nv = n_nodes[b] - nb0;                            // valid nodes in this chunk
    nv = nv < 0 ? 0 : (nv > NPB ? NPB : nv);

    if (t < NPB) keys_s[t] = -INFINITY;                   // tail default
    __syncthreads();

    const float4* __restrict__ h4 = (const float4*)h;
    // float4 index for (node, lane): node*64 + lane
    const long long idx = (base + wave) * 64 + lane;

    // Each iteration ii covers nodes [ii*4, ii*4+4) (one per wave).
    const int niter = (nv + 3) >> 2;                      // only valid prefix
    for (int ii = 0; ii < niter; ii += UNROLL) {
        float4 d[UNROLL];
        bool   act[UNROLL];
#pragma unroll
        for (int u = 0; u < UNROLL; ++u) {
            int local = (ii + u) * 4 + wave;              // wave-uniform
            act[u] = (local < nv) && (ii + u < niter);
            if (act[u])
                d[u] = h4[idx + (long long)(ii + u) * 4 * 64];
        }
#pragma unroll
        for (int u = 0; u < UNROLL; ++u) {
            if (act[u]) {                                 // wave-uniform branch
                float m = fmaxf(fmaxf(d[u].x, d[u].y), fmaxf(d[u].z, d[u].w));
#pragma unroll
                for (int off = 32; off > 0; off >>= 1)
                    m = fmaxf(m, __shfl_xor(m, off, 64));
                if (lane == 0)
                    keys_s[(ii + u) * 4 + wave] = m;
            }
        }
    }
    __syncthreads();
    if (t < NPB)
        keys[base + t] = keys_s[t];                       // coalesced 256 B store
}

// ---------------------------------------------------------------------------
// Kernel 2: one block (256 threads, 4 waves) per graph. 8 barriers total:
//   - keys held in registers (float4/thread); top-5 via packed uint64
//     (ordf(val)<<32 | (1023-idx)) so a single 64-bit max implements the
//     (val desc, idx asc) top_k tie-break; wave shfl butterfly + per-round
//     LDS slot -> 1 barrier/round (5 total).
//   - all 5 rows gathered concurrently (1 barrier), rank-sorted in ONE fused
//     float4 LDS scan (1 barrier after scatter).
//   - logits via wave shuffle reduce + one cross-wave LDS combine (1 barrier);
//     softmax computed redundantly per-thread in registers.
// Invalid rows (key == -inf) are zeroed but still participate in the softmax
// (matches reference: their logit is leaky_relu(c_b)).
// ---------------------------------------------------------------------------
__global__ __launch_bounds__(256) void topk_attn_kernel(
        const float* __restrict__ h,
        const float* __restrict__ q,
        const float* __restrict__ W,    // [2H] flat: W1 = W[0:H], W2 = W[H:2H]
        const float* __restrict__ keys,
        float* __restrict__ out) {
    __shared__ float cb_red[4];
    __shared__ unsigned long long wmax[KSEL][4];   // per-round slots: 1 barrier/round
    __shared__ __align__(16) float row_s[KSEL][HDIM];
    __shared__ __align__(16) float sorted_s[KSEL][HDIM];
    __shared__ float dred[4][KSEL];

    const int t    = threadIdx.x;
    const int lane = t & 63;
    const int wave = t >> 6;
    const int b    = blockIdx.x;

    // ---- register loads: 4 keys/thread, q, W1, W2 ----
    const float4 kv = ((const float4*)(keys + b * NNODES))[t];
    const float qv = q[b * HDIM + t];
    const float w1 = W[t];
    const float w2 = W[HDIM + t];

    // packed keys: high 32 = ordered float, low 32 = 1023-idx (asc-idx tiebreak)
    unsigned long long pk0 = ((unsigned long long)ordf(kv.x) << 32) | (unsigned int)(1023 - (4 * t + 0));
    unsigned long long pk1 = ((unsigned long long)ordf(kv.y) << 32) | (unsigned int)(1023 - (4 * t + 1));
    unsigned long long pk2 = ((unsigned long long)ordf(kv.z) << 32) | (unsigned int)(1023 - (4 * t + 2));
    unsigned long long pk3 = ((unsigned long long)ordf(kv.w) << 32) | (unsigned int)(1023 - (4 * t + 3));

    // ---- c_b partial: wave butterfly now, cross-wave combine read later ----
    float c = qv * w2;
#pragma unroll
    for (int off = 32; off > 0; off >>= 1)
        c += __shfl_xor(c, off, 64);
    if (lane == 0) cb_red[wave] = c;     // covered by round-0 barrier below

    // ---- top-5: 5 rounds, 1 barrier each ----
    const unsigned int ORD_NINF = 0x007FFFFFu;   // ordf(-inf)
    int widx[KSEL];
    int wvalid[KSEL];
#pragma unroll
    for (int k = 0; k < KSEL; ++k) {
        unsigned long long p = pk0;
        p = pk1 > p ? pk1 : p;
        p = pk2 > p ? pk2 : p;
        p = pk3 > p ? pk3 : p;
#pragma unroll
        for (int off = 32; off > 0; off >>= 1) {
            unsigned long long o = __shfl_xor(p, off, 64);
            p = o > p ? o : p;
        }
        if (lane == 0) wmax[k][wave] = p;
        __syncthreads();
        unsigned long long p0 = wmax[k][0], p1 = wmax[k][1];
        unsigned long long p2 = wmax[k][2], p3 = wmax[k][3];
        p = p0 > p1 ? p0 : p1;
        unsigned long long pq = p2 > p3 ? p2 : p3;
        p = pq > p ? pq : p;

        const int idx = 1023 - (int)(unsigned int)(p & 0xFFFFFFFFull);
        widx[k]   = idx;
        wvalid[k] = ((unsigned int)(p >> 32)) != ORD_NINF;

        // exclude winner (static indexing only — no scratch)
        const bool own = (idx >> 2) == t;
        const int  s   = idx & 3;
        pk0 = (own && s == 0) ? 0ull : pk0;
        pk1 = (own && s == 1) ? 0ull : pk1;
        pk2 = (own && s == 2) ? 0ull : pk2;
        pk3 = (own && s == 3) ? 0ull : pk3;
    }

    // ---- gather all 5 rows concurrently (loads pipelined, 1 barrier) ----
    float vk[KSEL];
#pragma unroll
    for (int k = 0; k < KSEL; ++k) {
        float v = 0.0f;
        if (wvalid[k])                                   // block-uniform branch
            v = h[((long long)b * NNODES + widx[k]) * HDIM + t];
        vk[k] = v;
    }
#pragma unroll
    for (int k = 0; k < KSEL; ++k)
        row_s[k][t] = vk[k];
    __syncthreads();

    // ---- fused rank-sort of all 5 rows (ascending, (val, idx) total order) ----
    int rk[KSEL] = {0, 0, 0, 0, 0};
    const float4* r4 = (const float4*)&row_s[0][0];      // [KSEL][HDIM/4]
#pragma unroll 4
    for (int jj = 0; jj < HDIM / 4; ++jj) {
        const int j = jj * 4;
#pragma unroll
        for (int k = 0; k < KSEL; ++k) {
            float4 a = r4[k * (HDIM / 4) + jj];          // uniform addr: LDS broadcast
            rk[k] += (int)((a.x < vk[k]) | ((a.x == vk[k]) & (j     < t)));
            rk[k] += (int)((a.y < vk[k]) | ((a.y == vk[k]) & (j + 1 < t)));
            rk[k] += (int)((a.z < vk[k]) | ((a.z == vk[k]) & (j + 2 < t)));
            rk[k] += (int)((a.w < vk[k]) | ((a.w == vk[k]) & (j + 3 < t)));
        }
    }
#pragma unroll
    for (int k = 0; k < KSEL; ++k)
        sorted_s[k][rk[k]] = vk[k];                      // bijection: total order
    __syncthreads();

    // ---- logits: 5 dots via wave shfl + one cross-wave combine ----
    float sv[KSEL], d[KSEL];
#pragma unroll
    for (int k = 0; k < KSEL; ++k) {
        sv[k] = sorted_s[k][t];
        d[k]  = sv[k] * w1;
    }
#pragma unroll
    for (int off = 32; off > 0; off >>= 1) {
#pragma unroll
        for (int k = 0; k < KSEL; ++k)
            d[k] += __shfl_xor(d[k], off, 64);
    }
    if (lane == 0) {
#pragma unroll
        for (int k = 0; k < KSEL; ++k)
            dred[wave][k] = d[k];
    }
    __syncthreads();

    // ---- leaky-relu + softmax, redundantly per-thread in registers ----
    const float cb = cb_red[0] + cb_red[1] + cb_red[2] + cb_red[3];
    float lg[KSEL];
    float mx = -INFINITY;
#pragma unroll
    for (int k = 0; k < KSEL; ++k) {
        float x = dred[0][k] + dred[1][k] + dred[2][k] + dred[3][k] + cb;
        lg[k] = (x > 0.0f) ? x : NEG_SLOPE * x;
        mx = fmaxf(mx, lg[k]);
    }
    float den = 0.0f;
#pragma unroll
    for (int k = 0; k < KSEL; ++k) { lg[k] = expf(lg[k] - mx); den += lg[k]; }
    const float inv_den = 1.0f / den;

    // ---- weighted sum, f32 store ----
    float o = 0.0f;
#pragma unroll
    for (int k = 0; k < KSEL; ++k)
        o += (lg[k] * inv_den) * sv[k];

    out[b * HDIM + t] = o;
}

extern "C" void kernel_launch(void* const* d_in, const int* in_sizes, int n_in,
                              void* d_out, int out_size, void* d_ws, size_t ws_size,
                              hipStream_t stream) {
    // Inputs (setup_inputs order, reference dtypes): h [B,N,H] f32,
    // n_nodes [B] int32, attention_query [B,H] f32, W [1,2H] f32.
    // Output: [B,H] f32.
    const float* h  = (const float*)d_in[0];
    const int*   nn = (const int*)d_in[1];
    const float* q  = (const float*)d_in[2];
    const float* W  = (const float*)d_in[3];
    float*       out = (float*)d_out;

    float* keys = (float*)d_ws;   // B*N floats = 1 MiB, fully overwritten every call

    // Pass 1: per-node max, reading ONLY the valid node prefix per graph
    // (~134 MB of 268 MB). 4096 blocks (2x residency) -> HW dispatcher
    // rebalances; swizzled 64-node chunks.
    node_max_kernel<<<(BGRAPHS * NNODES) / NPB, 256, 0, stream>>>(h, nn, keys);
    // Pass 2: per-graph top-5 + sort + attention (8 barriers total)
    topk_attn_kernel<<<BGRAPHS, 256, 0, stream>>>(h, q, W, keys, out);
}